// Round 6
// baseline (269.295 us; speedup 1.0000x reference)
//
#include <hip/hip_runtime.h>
#include <hip/hip_bf16.h>

// MHA forward: B=2, H=16, S=2048, D=1024, d_k=64, causal, RoPE(theta=1e4)
// R5 -> R6 (attn rework; GEMM/RoPE/cvt unchanged):
//  - q-block 128 = 4 waves x 32 q-rows (2 sub-tiles): kf/vf LDS reads amortized 2x
//  - staging via global_load_lds w16 with pre-swizzled GLOBAL src (involution),
//    LDS dest linear; issued at top of iter into buf^1 -> full-compute latency window
//  - LDS double-buffer, 1 barrier/iter
//  - grid (16,32): XCD-clustered (4 bh per XCD -> 2MB K/V in L2), heavy-first q-blocks

typedef __bf16 bf16x8 __attribute__((ext_vector_type(8)));
typedef __bf16 bf16x4 __attribute__((ext_vector_type(4)));
typedef float f32x4 __attribute__((ext_vector_type(4)));
typedef unsigned short ushort8 __attribute__((ext_vector_type(8)));

#define BATCH 2
#define SEQ 2048
#define NH 16
#define DK 64
#define DM 1024
#define BH (BATCH*NH)
#define M_TOT (BATCH*SEQ)   // 4096
#define QB 128              // q rows per attn block

__device__ __forceinline__ void gload16(const void* g, void* l) {
    // async global->LDS, 16B/lane; LDS dest = wave-uniform base + lane*16
    __builtin_amdgcn_global_load_lds((const __attribute__((address_space(1))) void*)g,
                                     (__attribute__((address_space(3))) void*)l, 16, 0, 0);
}

// ---------------- fp32 -> bf16 converts ----------------
__global__ void cvt_kernel(const float* __restrict__ s, __bf16* __restrict__ d, int n) {
    int i = (blockIdx.x * blockDim.x + threadIdx.x) * 4;
    if (i >= n) return;
    float4 v = *(const float4*)(s + i);
    bf16x4 o;
    o[0] = (__bf16)v.x; o[1] = (__bf16)v.y; o[2] = (__bf16)v.z; o[3] = (__bf16)v.w;
    *(bf16x4*)(d + i) = o;
}

__global__ void cvt4_kernel(const float* __restrict__ s0, const float* __restrict__ s1,
                            const float* __restrict__ s2, const float* __restrict__ s3,
                            __bf16* __restrict__ d0, __bf16* __restrict__ d1,
                            __bf16* __restrict__ d2, __bf16* __restrict__ d3, int n) {
    const int z = blockIdx.y;
    const float* s = (z == 0) ? s0 : (z == 1) ? s1 : (z == 2) ? s2 : s3;
    __bf16* d = (z == 0) ? d0 : (z == 1) ? d1 : (z == 2) ? d2 : d3;
    int i = (blockIdx.x * blockDim.x + threadIdx.x) * 4;
    if (i >= n) return;
    float4 v = *(const float4*)(s + i);
    bf16x4 o;
    o[0] = (__bf16)v.x; o[1] = (__bf16)v.y; o[2] = (__bf16)v.z; o[3] = (__bf16)v.w;
    *(bf16x4*)(d + i) = o;
}

// ---------------- GEMM core: C[128x128] = A[128xK] * W[128xK]^T ----------------
__device__ __forceinline__ void gemm_tile_compute(
    const __bf16* __restrict__ A, const __bf16* __restrict__ W,
    int m0, int n0, int K, __bf16* sA, __bf16* sB, f32x4 (&acc)[4][4])
{
    const int t = threadIdx.x;
    const int lane = t & 63, wid = t >> 6;
    const int wr = wid >> 1, wc = wid & 1;
    const int g = lane >> 4, l15 = lane & 15;

    f32x4 zero = {0.f, 0.f, 0.f, 0.f};
#pragma unroll
    for (int mt = 0; mt < 4; ++mt)
#pragma unroll
        for (int nt = 0; nt < 4; ++nt) acc[mt][nt] = zero;

    for (int k0 = 0; k0 < K; k0 += 32) {
        __syncthreads();
#pragma unroll
        for (int rnd = 0; rnd < 2; ++rnd) {
            int s = rnd * 256 + t;
            int row = s >> 2, ch = s & 3;
            __bf16* dstA = sA + (rnd * 256 + wid * 64) * 8;
            __bf16* dstB = sB + (rnd * 256 + wid * 64) * 8;
            gload16(A + (size_t)(m0 + row) * K + k0 + ch * 8, dstA);
            gload16(W + (size_t)(n0 + row) * K + k0 + ch * 8, dstB);
        }
        __syncthreads();
        bf16x8 af[4], bfr[4];
#pragma unroll
        for (int mt = 0; mt < 4; ++mt)
            af[mt] = *(const bf16x8*)&sA[(wr * 64 + mt * 16 + l15) * 32 + g * 8];
#pragma unroll
        for (int nt = 0; nt < 4; ++nt)
            bfr[nt] = *(const bf16x8*)&sB[(wc * 64 + nt * 16 + l15) * 32 + g * 8];
#pragma unroll
        for (int mt = 0; mt < 4; ++mt)
#pragma unroll
            for (int nt = 0; nt < 4; ++nt)
                acc[mt][nt] = __builtin_amdgcn_mfma_f32_16x16x32_bf16(af[mt], bfr[nt], acc[mt][nt], 0, 0, 0);
    }
}

// QKV GEMM: z=0 -> Q [B,H,S,dk], z=1 -> K [B,H,S,dk], z=2 -> V^T [B,H,dk,S]
__global__ __launch_bounds__(256) void gemm_qkv(
    const __bf16* __restrict__ xb,
    const __bf16* __restrict__ wq, const __bf16* __restrict__ wk, const __bf16* __restrict__ wv,
    __bf16* __restrict__ Qb, __bf16* __restrict__ Kb, __bf16* __restrict__ VTb)
{
    __shared__ __align__(16) __bf16 sA[128 * 32], sB[128 * 32];
    const int z = blockIdx.z;
    const __bf16* W = (z == 0) ? wq : ((z == 1) ? wk : wv);
    f32x4 acc[4][4];
    const int m0 = blockIdx.y * 128, n0 = blockIdx.x * 128;
    gemm_tile_compute(xb, W, m0, n0, DM, sA, sB, acc);

    const int t = threadIdx.x, lane = t & 63, wid = t >> 6;
    const int wr = wid >> 1, wc = wid & 1, g = lane >> 4, l15 = lane & 15;
    __bf16* QK = (z == 0) ? Qb : Kb;
#pragma unroll
    for (int mt = 0; mt < 4; ++mt)
#pragma unroll
        for (int nt = 0; nt < 4; ++nt)
#pragma unroll
            for (int r = 0; r < 4; ++r) {
                int m = m0 + wr * 64 + mt * 16 + g * 4 + r;   // (b, s)
                int n = n0 + wc * 64 + nt * 16 + l15;         // (h, d)
                int b = m >> 11, s = m & 2047, h = n >> 6, d = n & 63;
                __bf16 v = (__bf16)acc[mt][nt][r];
                if (z < 2)
                    QK[(((size_t)(b * NH + h)) * SEQ + s) * DK + d] = v;
                else
                    VTb[(((size_t)(b * NH + h)) * DK + d) * SEQ + s] = v;
            }
}

// Output GEMM: out[M,1024] fp32 = AO[M,1024]bf16 @ Wo^T
__global__ __launch_bounds__(256) void gemm_out(
    const __bf16* __restrict__ AO, const __bf16* __restrict__ wo, float* __restrict__ out)
{
    __shared__ __align__(16) __bf16 sA[128 * 32], sB[128 * 32];
    f32x4 acc[4][4];
    const int m0 = blockIdx.y * 128, n0 = blockIdx.x * 128;
    gemm_tile_compute(AO, wo, m0, n0, DM, sA, sB, acc);

    const int t = threadIdx.x, lane = t & 63, wid = t >> 6;
    const int wr = wid >> 1, wc = wid & 1, g = lane >> 4, l15 = lane & 15;
#pragma unroll
    for (int mt = 0; mt < 4; ++mt)
#pragma unroll
        for (int nt = 0; nt < 4; ++nt)
#pragma unroll
            for (int r = 0; r < 4; ++r) {
                int m = m0 + wr * 64 + mt * 16 + g * 4 + r;
                int n = n0 + wc * 64 + nt * 16 + l15;
                out[(size_t)m * DM + n] = acc[mt][nt][r];
            }
}

// ---------------- RoPE (in-place on Q,K bf16 [B,H,S,dk]) ----------------
__global__ __launch_bounds__(256) void rope_kernel(
    __bf16* __restrict__ Qb, __bf16* __restrict__ Kb, const int* __restrict__ pos)
{
    __shared__ float ctab[32], stab[32];
    const int s = blockIdx.x;
    const int t = threadIdx.x;
    if (t < 32) {
        float invf = exp2f(-13.287712379549449f * (float)t * (1.0f / 32.0f));
        float ang = (float)pos[s] * invf;
        float sn, cs;
        sincosf(ang, &sn, &cs);
        ctab[t] = cs; stab[t] = sn;
    }
    __syncthreads();
#pragma unroll
    for (int u = 0; u < 8; ++u) {
        int id = u * 256 + t;
        int i = id & 31;
        int bh = (id >> 5) & 31;
        __bf16* P = (id >> 10) ? Kb : Qb;
        __bf16* p = P + ((size_t)bh * SEQ + s) * DK + i * 2;
        float x1 = (float)p[0], x2 = (float)p[1];
        float c = ctab[i], sn = stab[i];
        p[0] = (__bf16)(x1 * c - x2 * sn);
        p[1] = (__bf16)(x1 * sn + x2 * c);
    }
}

// ---------------- Flash attention ----------------
// grid (16, 32) -> n = bx + 16*by; xcd = n&7 owns 4 bh entirely (L2 locality);
// q-block j = 15 - (slot&15) heavy-first. Block: 4 waves x 32 q-rows (2 subs of 16).
// LDS: K/V double-buffered [2][64][64] linear rows, XOR-swizzled chunks
// (swizzle applied on the GLOBAL source address; global_load_lds dest stays linear).
__global__ __launch_bounds__(256, 3) void attn_kernel(
    const __bf16* __restrict__ Qb, const __bf16* __restrict__ Kb,
    const __bf16* __restrict__ VTb, __bf16* __restrict__ AO)
{
    __shared__ __align__(16) __bf16 sK[2][64 * 64];       // [buf][kv][d] swizzled
    __shared__ __align__(16) __bf16 sV[2][64 * 64];       // [buf][d][kv] swizzled
    __shared__ __align__(16) __bf16 sP[4 * 2 * 16 * 64];  // [wave][sub][16][64] swizzled

    const int n = blockIdx.x + 16 * blockIdx.y;           // 0..511
    const int xcd = n & 7, slot = n >> 3;                 // 64 slots per XCD
    const int bh = xcd * 4 + (slot >> 4);
    const int j = 15 - (slot & 15);                       // q-block, heavy-first
    const int t = threadIdx.x, lane = t & 63, wid = t >> 6;
    const int g = lane >> 4, l15 = lane & 15;

    const size_t baseQK = (size_t)bh * SEQ * DK;
    const size_t baseVT = (size_t)bh * DK * SEQ;
    const int b = bh >> 4, h = bh & 15;
    const int qrow_w = j * QB + wid * 32;                 // wave's first q row

    // Q fragments [sub][ks], held in regs for the whole kv loop
    bf16x8 qf[2][2];
#pragma unroll
    for (int s = 0; s < 2; ++s) {
        const __bf16* qp = Qb + baseQK + (size_t)(qrow_w + s * 16 + l15) * DK;
        qf[s][0] = *(const bf16x8*)(qp + g * 8);
        qf[s][1] = *(const bf16x8*)(qp + 32 + g * 8);
    }

    f32x4 zero = {0.f, 0.f, 0.f, 0.f};
    f32x4 oacc[2][4];
    float mrow[2][4], lrow[2][4];
#pragma unroll
    for (int s = 0; s < 2; ++s)
#pragma unroll
        for (int r = 0; r < 4; ++r) {
            oacc[s][r] = zero;            // (f32x4 per dt; init all dt below)
        }
#pragma unroll
    for (int s = 0; s < 2; ++s)
#pragma unroll
        for (int dt = 0; dt < 4; ++dt) oacc[s][dt] = zero;
#pragma unroll
    for (int s = 0; s < 2; ++s)
#pragma unroll
        for (int r = 0; r < 4; ++r) { mrow[s][r] = -3e38f; lrow[s][r] = 0.f; }

    const char* Kt0 = (const char*)(Kb + baseQK);
    const char* Vt0 = (const char*)(VTb + baseVT);
    const int ktmax = 2 * j + 1;

    // async stage tile kt into buffer bq: linear LDS dest, inverse-swizzled global src
    auto stage_tile = [&](int kt, int bq) {
        const char* Kt = Kt0 + (size_t)kt * 64 * 128;
        const char* Vt = Vt0 + (size_t)kt * 128;
#pragma unroll
        for (int cc = 0; cc < 2; ++cc) {
            int c = t + cc * 256;                 // linear LDS 16B slot
            int r = c >> 3, pp = c & 7;
            int p = pp ^ (r & 7);                 // involution: src chunk
            char* bK = (char*)sK[bq] + (cc * 256 + wid * 64) * 16;  // wave-uniform
            char* bV = (char*)sV[bq] + (cc * 256 + wid * 64) * 16;
            gload16(Kt + (size_t)r * 128 + p * 16, bK);
            gload16(Vt + (size_t)r * (SEQ * 2) + p * 16, bV);
        }
    };

    stage_tile(0, 0);
    __syncthreads();      // drains vmcnt -> buf0 valid
    int cur = 0;

    for (int kt = 0; kt <= ktmax; ++kt) {
        if (kt < ktmax) stage_tile(kt + 1, cur ^ 1);   // DMA into other buf, overlaps

        // ---- QK^T: kf read once, used by both q-subs ----
        f32x4 sacc[2][4];
#pragma unroll
        for (int s = 0; s < 2; ++s)
#pragma unroll
            for (int nt = 0; nt < 4; ++nt) sacc[s][nt] = zero;
#pragma unroll
        for (int nt = 0; nt < 4; ++nt) {
            int row = nt * 16 + l15;
#pragma unroll
            for (int ks = 0; ks < 2; ++ks) {
                bf16x8 kf = *(const bf16x8*)((const char*)sK[cur] + row * 128 +
                                             ((ks * 64 + g * 16) ^ ((row & 7) << 4)));
                sacc[0][nt] = __builtin_amdgcn_mfma_f32_16x16x32_bf16(qf[0][ks], kf, sacc[0][nt], 0, 0, 0);
                sacc[1][nt] = __builtin_amdgcn_mfma_f32_16x16x32_bf16(qf[1][ks], kf, sacc[1][nt], 0, 0, 0);
            }
        }

        // ---- mask + online softmax + P-write, per sub ----
#pragma unroll
        for (int s = 0; s < 2; ++s) {
            const int q0 = qrow_w + s * 16;
            if (kt * 64 + 63 > q0) {              // tile crosses/exceeds diagonal
#pragma unroll
                for (int nt = 0; nt < 4; ++nt)
#pragma unroll
                    for (int r = 0; r < 4; ++r) {
                        int kv = kt * 64 + nt * 16 + l15;
                        int q = q0 + g * 4 + r;
                        if (kv > q) sacc[s][nt][r] = -3e38f; else sacc[s][nt][r] *= 0.125f;
                    }
            } else {
#pragma unroll
                for (int nt = 0; nt < 4; ++nt)
#pragma unroll
                    for (int r = 0; r < 4; ++r) sacc[s][nt][r] *= 0.125f;
            }
#pragma unroll
            for (int r = 0; r < 4; ++r) {
                float tm = fmaxf(fmaxf(sacc[s][0][r], sacc[s][1][r]),
                                 fmaxf(sacc[s][2][r], sacc[s][3][r]));
#pragma unroll
                for (int msk = 1; msk < 16; msk <<= 1) tm = fmaxf(tm, __shfl_xor(tm, msk));
                float mnew = fmaxf(mrow[s][r], tm);
                float sc = __expf(mrow[s][r] - mnew);
                float rs = 0.f;
#pragma unroll
                for (int nt = 0; nt < 4; ++nt) {
                    float p = __expf(sacc[s][nt][r] - mnew);
                    sacc[s][nt][r] = p;
                    rs += p;
                }
#pragma unroll
                for (int msk = 1; msk < 16; msk <<= 1) rs += __shfl_xor(rs, msk);
                lrow[s][r] = lrow[s][r] * sc + rs;
                mrow[s][r] = mnew;
#pragma unroll
                for (int dt = 0; dt < 4; ++dt) oacc[s][dt][r] *= sc;
            }
            // P -> per-wave-sub LDS (swizzled); same-wave DS in-order, no barrier
            char* myP = (char*)sP + (wid * 2 + s) * 2048;
#pragma unroll
            for (int nt = 0; nt < 4; ++nt)
#pragma unroll
                for (int r = 0; r < 4; ++r) {
                    int row = g * 4 + r;
                    *(__bf16*)(myP + row * 128 +
                               ((nt * 32 + l15 * 2) ^ ((row & 7) << 4))) = (__bf16)sacc[s][nt][r];
                }
        }

        // ---- PV: vf read once, used by both q-subs ----
#pragma unroll
        for (int ks = 0; ks < 2; ++ks) {
            bf16x8 pf[2];
#pragma unroll
            for (int s = 0; s < 2; ++s)
                pf[s] = *(const bf16x8*)((char*)sP + (wid * 2 + s) * 2048 + l15 * 128 +
                                         ((ks * 64 + g * 16) ^ ((l15 & 7) << 4)));
#pragma unroll
            for (int dt = 0; dt < 4; ++dt) {
                int row = dt * 16 + l15;
                bf16x8 vf = *(const bf16x8*)((const char*)sV[cur] + row * 128 +
                                             ((ks * 64 + g * 16) ^ ((row & 7) << 4)));
                oacc[0][dt] = __builtin_amdgcn_mfma_f32_16x16x32_bf16(pf[0], vf, oacc[0][dt], 0, 0, 0);
                oacc[1][dt] = __builtin_amdgcn_mfma_f32_16x16x32_bf16(pf[1], vf, oacc[1][dt], 0, 0, 0);
            }
        }

        __syncthreads();   // drains DMA (next buf ready) + all waves done with cur
        cur ^= 1;
    }

    // epilogue: O /= l, write AO [b][s][h*64+d]
#pragma unroll
    for (int s = 0; s < 2; ++s)
#pragma unroll
        for (int r = 0; r < 4; ++r) {
            float inv = 1.0f / lrow[s][r];
            int srow = qrow_w + s * 16 + g * 4 + r;
            size_t obase = ((size_t)b * SEQ + srow) * DM + h * DK;
#pragma unroll
            for (int dt = 0; dt < 4; ++dt)
                AO[obase + dt * 16 + l15] = (__bf16)(oacc[s][dt][r] * inv);
        }
}

// ---------------- launch ----------------
extern "C" void kernel_launch(void* const* d_in, const int* in_sizes, int n_in,
                              void* d_out, int out_size, void* d_ws, size_t ws_size,
                              hipStream_t stream) {
    (void)in_sizes; (void)n_in; (void)out_size; (void)ws_size;
    const float* x  = (const float*)d_in[0];
    const int*  pos = (const int*)d_in[1];
    const float* Wq = (const float*)d_in[2];
    const float* Wk = (const float*)d_in[3];
    const float* Wv = (const float*)d_in[4];
    const float* Wo = (const float*)d_in[5];
    float* out = (float*)d_out;

    char* ws = (char*)d_ws;
    __bf16* xb  = (__bf16*)ws; ws += (size_t)M_TOT * DM * 2;
    __bf16* wqb = (__bf16*)ws; ws += (size_t)DM * DM * 2;
    __bf16* wkb = (__bf16*)ws; ws += (size_t)DM * DM * 2;
    __bf16* wvb = (__bf16*)ws; ws += (size_t)DM * DM * 2;
    __bf16* wob = (__bf16*)ws; ws += (size_t)DM * DM * 2;
    __bf16* Qb  = (__bf16*)ws; ws += (size_t)BH * SEQ * DK * 2;
    __bf16* Kb  = (__bf16*)ws; ws += (size_t)BH * SEQ * DK * 2;
    __bf16* VTb = (__bf16*)ws; ws += (size_t)BH * SEQ * DK * 2;
    __bf16* AOb = (__bf16*)ws; ws += (size_t)M_TOT * DM * 2;

    const int nx = M_TOT * DM, nw = DM * DM;
    cvt_kernel<<<nx / 4 / 256, 256, 0, stream>>>(x, xb, nx);
    cvt4_kernel<<<dim3(nw / 4 / 256, 4), 256, 0, stream>>>(Wq, Wk, Wv, Wo, wqb, wkb, wvb, wob, nw);

    gemm_qkv<<<dim3(DM / 128, M_TOT / 128, 3), 256, 0, stream>>>(xb, wqb, wkb, wvb, Qb, Kb, VTb);
    rope_kernel<<<SEQ, 256, 0, stream>>>(Qb, Kb, pos);
    attn_kernel<<<dim3(16, BH), 256, 0, stream>>>(Qb, Kb, VTb, AOb);
    gemm_out<<<dim3(DM / 128, M_TOT / 128), 256, 0, stream>>>(AOb, wob, out);
}

// Round 7
// 263.043 us; speedup vs baseline: 1.0238x; 1.0238x over previous
//
#include <hip/hip_runtime.h>
#include <hip/hip_bf16.h>

// MHA forward: B=2, H=16, S=2048, D=1024, d_k=64, causal, RoPE(theta=1e4)
// R6 -> R7:
//  - attn: keep R6 internals (q-block 128, kf/vf amortized 2x, DMA dbuf, swizzle),
//          but balanced pair phases {x,15-x} = 34 iters/block constant,
//          XCD-clustered grid 256 = 8 pairs x 32 bh (4 bh per XCD).
//  - gemm: BK=64 (halves barriers) + chunk-XOR swizzle (same geometry attn measured
//          at 0 conflicts); QKV merged into one dispatch ([3072][1024] weights),
//          XCD-swizzled block ids.

typedef __bf16 bf16x8 __attribute__((ext_vector_type(8)));
typedef __bf16 bf16x4 __attribute__((ext_vector_type(4)));
typedef float f32x4 __attribute__((ext_vector_type(4)));
typedef unsigned short ushort8 __attribute__((ext_vector_type(8)));

#define BATCH 2
#define SEQ 2048
#define NH 16
#define DK 64
#define DM 1024
#define BH (BATCH*NH)
#define M_TOT (BATCH*SEQ)   // 4096
#define QB 128              // q rows per attn block

__device__ __forceinline__ void gload16(const void* g, void* l) {
    // async global->LDS, 16B/lane; LDS dest = wave-uniform base + lane*16
    __builtin_amdgcn_global_load_lds((const __attribute__((address_space(1))) void*)g,
                                     (__attribute__((address_space(3))) void*)l, 16, 0, 0);
}

// ---------------- fp32 -> bf16 converts ----------------
__global__ void cvt_kernel(const float* __restrict__ s, __bf16* __restrict__ d, int n) {
    int i = (blockIdx.x * blockDim.x + threadIdx.x) * 4;
    if (i >= n) return;
    float4 v = *(const float4*)(s + i);
    bf16x4 o;
    o[0] = (__bf16)v.x; o[1] = (__bf16)v.y; o[2] = (__bf16)v.z; o[3] = (__bf16)v.w;
    *(bf16x4*)(d + i) = o;
}

__global__ void cvt4_kernel(const float* __restrict__ s0, const float* __restrict__ s1,
                            const float* __restrict__ s2, const float* __restrict__ s3,
                            __bf16* __restrict__ d0, __bf16* __restrict__ d1,
                            __bf16* __restrict__ d2, __bf16* __restrict__ d3, int n) {
    const int z = blockIdx.y;
    const float* s = (z == 0) ? s0 : (z == 1) ? s1 : (z == 2) ? s2 : s3;
    __bf16* d = (z == 0) ? d0 : (z == 1) ? d1 : (z == 2) ? d2 : d3;
    int i = (blockIdx.x * blockDim.x + threadIdx.x) * 4;
    if (i >= n) return;
    float4 v = *(const float4*)(s + i);
    bf16x4 o;
    o[0] = (__bf16)v.x; o[1] = (__bf16)v.y; o[2] = (__bf16)v.z; o[3] = (__bf16)v.w;
    *(bf16x4*)(d + i) = o;
}

// ---------------- GEMM core: C[128x128] = A[128xK] * W[128xK]^T ----------------
// BK=64, LDS rows 128B, chunk-XOR swizzle (involution on global src; linear LDS dest).
__device__ __forceinline__ void gemm_tile_compute(
    const __bf16* __restrict__ A, const __bf16* __restrict__ W,
    int m0, int n0, int K, __bf16* sA, __bf16* sB, f32x4 (&acc)[4][4])
{
    const int t = threadIdx.x;
    const int lane = t & 63, wid = t >> 6;
    const int wr = wid >> 1, wc = wid & 1;
    const int g = lane >> 4, l15 = lane & 15;

    f32x4 zero = {0.f, 0.f, 0.f, 0.f};
#pragma unroll
    for (int mt = 0; mt < 4; ++mt)
#pragma unroll
        for (int nt = 0; nt < 4; ++nt) acc[mt][nt] = zero;

    for (int k0 = 0; k0 < K; k0 += 64) {
        __syncthreads();
        // stage [128 rows][64 bf16] per matrix = 1024 16B-chunks -> 4 rounds
#pragma unroll
        for (int rnd = 0; rnd < 4; ++rnd) {
            int slot = rnd * 256 + t;            // linear LDS 16B slot 0..1023
            int row = slot >> 3, pp = slot & 7;
            int p = pp ^ (row & 7);              // involution: source chunk
            char* dA = (char*)sA + (rnd * 256 + wid * 64) * 16;  // wave-uniform
            char* dB = (char*)sB + (rnd * 256 + wid * 64) * 16;
            gload16((const char*)(A + (size_t)(m0 + row) * K + k0) + p * 16, dA);
            gload16((const char*)(W + (size_t)(n0 + row) * K + k0) + p * 16, dB);
        }
        __syncthreads();
#pragma unroll
        for (int ks = 0; ks < 2; ++ks) {
            bf16x8 af[4], bfr[4];
#pragma unroll
            for (int mt = 0; mt < 4; ++mt) {
                int row = wr * 64 + mt * 16 + l15;
                af[mt] = *(const bf16x8*)((char*)sA + row * 128 +
                                          ((ks * 64 + g * 16) ^ ((row & 7) << 4)));
            }
#pragma unroll
            for (int nt = 0; nt < 4; ++nt) {
                int row = wc * 64 + nt * 16 + l15;
                bfr[nt] = *(const bf16x8*)((char*)sB + row * 128 +
                                           ((ks * 64 + g * 16) ^ ((row & 7) << 4)));
            }
#pragma unroll
            for (int mt = 0; mt < 4; ++mt)
#pragma unroll
                for (int nt = 0; nt < 4; ++nt)
                    acc[mt][nt] = __builtin_amdgcn_mfma_f32_16x16x32_bf16(af[mt], bfr[nt], acc[mt][nt], 0, 0, 0);
        }
    }
}

// Merged QKV GEMM: W = [Wq;Wk;Wv] rows 0..3071. Routes to Q/K [B,H,S,dk], V^T [B,H,dk,S].
__global__ __launch_bounds__(256) void gemm_qkv(
    const __bf16* __restrict__ xb, const __bf16* __restrict__ wqkv,
    __bf16* __restrict__ Qb, __bf16* __restrict__ Kb, __bf16* __restrict__ VTb)
{
    __shared__ __align__(16) __bf16 sA[128 * 64], sB[128 * 64];
    int id = blockIdx.x + 24 * blockIdx.y;       // 0..767
    id = (id & 7) * 96 + (id >> 3);              // XCD-contiguous (768%8==0, bijective)
    const int m0 = (id / 24) * 128, n0 = (id % 24) * 128;

    f32x4 acc[4][4];
    gemm_tile_compute(xb, wqkv, m0, n0, DM, sA, sB, acc);

    const int t = threadIdx.x, lane = t & 63, wid = t >> 6;
    const int wr = wid >> 1, wc = wid & 1, g = lane >> 4, l15 = lane & 15;
#pragma unroll
    for (int mt = 0; mt < 4; ++mt)
#pragma unroll
        for (int nt = 0; nt < 4; ++nt)
#pragma unroll
            for (int r = 0; r < 4; ++r) {
                int m = m0 + wr * 64 + mt * 16 + g * 4 + r;   // (b, s)
                int n = n0 + wc * 64 + nt * 16 + l15;         // 0..3071
                int z = n >> 10, hd = n & 1023, h = hd >> 6, d = hd & 63;
                int b = m >> 11, s = m & 2047;
                __bf16 v = (__bf16)acc[mt][nt][r];
                if (z == 0)
                    Qb[(((size_t)(b * NH + h)) * SEQ + s) * DK + d] = v;
                else if (z == 1)
                    Kb[(((size_t)(b * NH + h)) * SEQ + s) * DK + d] = v;
                else
                    VTb[(((size_t)(b * NH + h)) * DK + d) * SEQ + s] = v;
            }
}

// Output GEMM: out[M,1024] fp32 = AO[M,1024]bf16 @ Wo^T
__global__ __launch_bounds__(256) void gemm_out(
    const __bf16* __restrict__ AO, const __bf16* __restrict__ wo, float* __restrict__ out)
{
    __shared__ __align__(16) __bf16 sA[128 * 64], sB[128 * 64];
    int id = blockIdx.x + 8 * blockIdx.y;        // 0..255
    id = (id & 7) * 32 + (id >> 3);              // XCD-contiguous (256%8==0)
    const int m0 = (id / 8) * 128, n0 = (id % 8) * 128;

    f32x4 acc[4][4];
    gemm_tile_compute(AO, wo, m0, n0, DM, sA, sB, acc);

    const int t = threadIdx.x, lane = t & 63, wid = t >> 6;
    const int wr = wid >> 1, wc = wid & 1, g = lane >> 4, l15 = lane & 15;
#pragma unroll
    for (int mt = 0; mt < 4; ++mt)
#pragma unroll
        for (int nt = 0; nt < 4; ++nt)
#pragma unroll
            for (int r = 0; r < 4; ++r) {
                int m = m0 + wr * 64 + mt * 16 + g * 4 + r;
                int n = n0 + wc * 64 + nt * 16 + l15;
                out[(size_t)m * DM + n] = acc[mt][nt][r];
            }
}

// ---------------- RoPE (in-place on Q,K bf16 [B,H,S,dk]) ----------------
__global__ __launch_bounds__(256) void rope_kernel(
    __bf16* __restrict__ Qb, __bf16* __restrict__ Kb, const int* __restrict__ pos)
{
    __shared__ float ctab[32], stab[32];
    const int s = blockIdx.x;
    const int t = threadIdx.x;
    if (t < 32) {
        float invf = exp2f(-13.287712379549449f * (float)t * (1.0f / 32.0f));
        float ang = (float)pos[s] * invf;
        float sn, cs;
        sincosf(ang, &sn, &cs);
        ctab[t] = cs; stab[t] = sn;
    }
    __syncthreads();
#pragma unroll
    for (int u = 0; u < 8; ++u) {
        int id = u * 256 + t;
        int i = id & 31;
        int bh = (id >> 5) & 31;
        __bf16* P = (id >> 10) ? Kb : Qb;
        __bf16* p = P + ((size_t)bh * SEQ + s) * DK + i * 2;
        float x1 = (float)p[0], x2 = (float)p[1];
        float c = ctab[i], sn = stab[i];
        p[0] = (__bf16)(x1 * c - x2 * sn);
        p[1] = (__bf16)(x1 * sn + x2 * c);
    }
}

// ---------------- Flash attention ----------------
// grid 256: n -> xcd = n&7 (4 bh per XCD, L2-resident K/V), slot = n>>3,
// bh = xcd*4 + slot>>3, x = slot&7. Two balanced phases: j = x then 15-x
// -> (2x+2) + (2(15-x)+2) = 34 iters for EVERY block.
// Block: 4 waves x 32 q-rows (2 subs of 16); kf/vf LDS reads shared by both subs.
// K/V double-buffered, DMA-staged (linear LDS dest, inverse-swizzled global src).
__global__ __launch_bounds__(256) void attn_kernel(
    const __bf16* __restrict__ Qb, const __bf16* __restrict__ Kb,
    const __bf16* __restrict__ VTb, __bf16* __restrict__ AO)
{
    __shared__ __align__(16) __bf16 sK[2][64 * 64];       // [buf][kv][d] swizzled
    __shared__ __align__(16) __bf16 sV[2][64 * 64];       // [buf][d][kv] swizzled
    __shared__ __align__(16) __bf16 sP[4 * 2 * 16 * 64];  // [wave][sub][16][64] swizzled

    const int n = blockIdx.x;                  // 0..255
    const int xcd = n & 7, slot = n >> 3;      // 32 slots per XCD
    const int bh = xcd * 4 + (slot >> 3);
    const int x = slot & 7;                    // pair index 0..7
    const int t = threadIdx.x, lane = t & 63, wid = t >> 6;
    const int g = lane >> 4, l15 = lane & 15;

    const size_t baseQK = (size_t)bh * SEQ * DK;
    const size_t baseVT = (size_t)bh * DK * SEQ;
    const int b = bh >> 4, h = bh & 15;

    const char* Kt0 = (const char*)(Kb + baseQK);
    const char* Vt0 = (const char*)(VTb + baseVT);
    f32x4 zero = {0.f, 0.f, 0.f, 0.f};

    // async stage tile kt into buffer bq: linear LDS dest, inverse-swizzled global src
    auto stage_tile = [&](int kt, int bq) {
        const char* Kt = Kt0 + (size_t)kt * 64 * 128;
        const char* Vt = Vt0 + (size_t)kt * 128;
#pragma unroll
        for (int cc = 0; cc < 2; ++cc) {
            int c = t + cc * 256;
            int r = c >> 3, pp = c & 7;
            int p = pp ^ (r & 7);
            char* bK = (char*)sK[bq] + (cc * 256 + wid * 64) * 16;
            char* bV = (char*)sV[bq] + (cc * 256 + wid * 64) * 16;
            gload16(Kt + (size_t)r * 128 + p * 16, bK);
            gload16(Vt + (size_t)r * (SEQ * 2) + p * 16, bV);
        }
    };

    for (int ph = 0; ph < 2; ++ph) {
        const int j = ph ? (15 - x) : x;
        const int qrow_w = j * QB + wid * 32;
        const int ktmax = 2 * j + 1;

        // Q fragments [sub][ks]
        bf16x8 qf[2][2];
#pragma unroll
        for (int s = 0; s < 2; ++s) {
            const __bf16* qp = Qb + baseQK + (size_t)(qrow_w + s * 16 + l15) * DK;
            qf[s][0] = *(const bf16x8*)(qp + g * 8);
            qf[s][1] = *(const bf16x8*)(qp + 32 + g * 8);
        }

        f32x4 oacc[2][4];
        float mrow[2][4], lrow[2][4];
#pragma unroll
        for (int s = 0; s < 2; ++s)
#pragma unroll
            for (int dt = 0; dt < 4; ++dt) oacc[s][dt] = zero;
#pragma unroll
        for (int s = 0; s < 2; ++s)
#pragma unroll
            for (int r = 0; r < 4; ++r) { mrow[s][r] = -3e38f; lrow[s][r] = 0.f; }

        stage_tile(0, 0);
        __syncthreads();      // drains vmcnt -> buf0 valid
        int cur = 0;

        for (int kt = 0; kt <= ktmax; ++kt) {
            if (kt < ktmax) stage_tile(kt + 1, cur ^ 1);   // DMA overlaps compute

            // ---- QK^T: kf read once, used by both q-subs ----
            f32x4 sacc[2][4];
#pragma unroll
            for (int s = 0; s < 2; ++s)
#pragma unroll
                for (int nt = 0; nt < 4; ++nt) sacc[s][nt] = zero;
#pragma unroll
            for (int nt = 0; nt < 4; ++nt) {
                int row = nt * 16 + l15;
#pragma unroll
                for (int ks = 0; ks < 2; ++ks) {
                    bf16x8 kf = *(const bf16x8*)((const char*)sK[cur] + row * 128 +
                                                 ((ks * 64 + g * 16) ^ ((row & 7) << 4)));
                    sacc[0][nt] = __builtin_amdgcn_mfma_f32_16x16x32_bf16(qf[0][ks], kf, sacc[0][nt], 0, 0, 0);
                    sacc[1][nt] = __builtin_amdgcn_mfma_f32_16x16x32_bf16(qf[1][ks], kf, sacc[1][nt], 0, 0, 0);
                }
            }

            // ---- mask + online softmax + P-write, per sub ----
#pragma unroll
            for (int s = 0; s < 2; ++s) {
                const int q0 = qrow_w + s * 16;
                if (kt * 64 + 63 > q0) {
#pragma unroll
                    for (int nt = 0; nt < 4; ++nt)
#pragma unroll
                        for (int r = 0; r < 4; ++r) {
                            int kv = kt * 64 + nt * 16 + l15;
                            int q = q0 + g * 4 + r;
                            if (kv > q) sacc[s][nt][r] = -3e38f; else sacc[s][nt][r] *= 0.125f;
                        }
                } else {
#pragma unroll
                    for (int nt = 0; nt < 4; ++nt)
#pragma unroll
                        for (int r = 0; r < 4; ++r) sacc[s][nt][r] *= 0.125f;
                }
#pragma unroll
                for (int r = 0; r < 4; ++r) {
                    float tm = fmaxf(fmaxf(sacc[s][0][r], sacc[s][1][r]),
                                     fmaxf(sacc[s][2][r], sacc[s][3][r]));
#pragma unroll
                    for (int msk = 1; msk < 16; msk <<= 1) tm = fmaxf(tm, __shfl_xor(tm, msk));
                    float mnew = fmaxf(mrow[s][r], tm);
                    float sc = __expf(mrow[s][r] - mnew);
                    float rs = 0.f;
#pragma unroll
                    for (int nt = 0; nt < 4; ++nt) {
                        float p = __expf(sacc[s][nt][r] - mnew);
                        sacc[s][nt][r] = p;
                        rs += p;
                    }
#pragma unroll
                    for (int msk = 1; msk < 16; msk <<= 1) rs += __shfl_xor(rs, msk);
                    lrow[s][r] = lrow[s][r] * sc + rs;
                    mrow[s][r] = mnew;
#pragma unroll
                    for (int dt = 0; dt < 4; ++dt) oacc[s][dt][r] *= sc;
                }
                // P -> per-wave-sub LDS (swizzled); same-wave DS in-order, no barrier
                char* myP = (char*)sP + (wid * 2 + s) * 2048;
#pragma unroll
                for (int nt = 0; nt < 4; ++nt)
#pragma unroll
                    for (int r = 0; r < 4; ++r) {
                        int row = g * 4 + r;
                        *(__bf16*)(myP + row * 128 +
                                   ((nt * 32 + l15 * 2) ^ ((row & 7) << 4))) = (__bf16)sacc[s][nt][r];
                    }
            }

            // ---- PV: vf read once, used by both q-subs ----
#pragma unroll
            for (int ks = 0; ks < 2; ++ks) {
                bf16x8 pf[2];
#pragma unroll
                for (int s = 0; s < 2; ++s)
                    pf[s] = *(const bf16x8*)((char*)sP + (wid * 2 + s) * 2048 + l15 * 128 +
                                             ((ks * 64 + g * 16) ^ ((l15 & 7) << 4)));
#pragma unroll
                for (int dt = 0; dt < 4; ++dt) {
                    int row = dt * 16 + l15;
                    bf16x8 vf = *(const bf16x8*)((const char*)sV[cur] + row * 128 +
                                                 ((ks * 64 + g * 16) ^ ((row & 7) << 4)));
                    oacc[0][dt] = __builtin_amdgcn_mfma_f32_16x16x32_bf16(pf[0], vf, oacc[0][dt], 0, 0, 0);
                    oacc[1][dt] = __builtin_amdgcn_mfma_f32_16x16x32_bf16(pf[1], vf, oacc[1][dt], 0, 0, 0);
                }
            }

            __syncthreads();   // drains DMA (next buf ready) + all waves done with cur
            cur ^= 1;
        }

        // epilogue: O /= l, write AO [b][s][h*64+d]
#pragma unroll
        for (int s = 0; s < 2; ++s)
#pragma unroll
            for (int r = 0; r < 4; ++r) {
                float inv = 1.0f / lrow[s][r];
                int srow = qrow_w + s * 16 + g * 4 + r;
                size_t obase = ((size_t)b * SEQ + srow) * DM + h * DK;
#pragma unroll
                for (int dt = 0; dt < 4; ++dt)
                    AO[obase + dt * 16 + l15] = (__bf16)(oacc[s][dt][r] * inv);
            }
    }
}

// ---------------- launch ----------------
extern "C" void kernel_launch(void* const* d_in, const int* in_sizes, int n_in,
                              void* d_out, int out_size, void* d_ws, size_t ws_size,
                              hipStream_t stream) {
    (void)in_sizes; (void)n_in; (void)out_size; (void)ws_size;
    const float* x  = (const float*)d_in[0];
    const int*  pos = (const int*)d_in[1];
    const float* Wq = (const float*)d_in[2];
    const float* Wk = (const float*)d_in[3];
    const float* Wv = (const float*)d_in[4];
    const float* Wo = (const float*)d_in[5];
    float* out = (float*)d_out;

    char* ws = (char*)d_ws;
    __bf16* xb   = (__bf16*)ws; ws += (size_t)M_TOT * DM * 2;
    __bf16* wqkv = (__bf16*)ws; ws += (size_t)3 * DM * DM * 2;
    __bf16* wob  = (__bf16*)ws; ws += (size_t)DM * DM * 2;
    __bf16* Qb   = (__bf16*)ws; ws += (size_t)BH * SEQ * DK * 2;
    __bf16* Kb   = (__bf16*)ws; ws += (size_t)BH * SEQ * DK * 2;
    __bf16* VTb  = (__bf16*)ws; ws += (size_t)BH * SEQ * DK * 2;
    __bf16* AOb  = (__bf16*)ws; ws += (size_t)M_TOT * DM * 2;

    const int nx = M_TOT * DM, nw = DM * DM;
    cvt_kernel<<<nx / 4 / 256, 256, 0, stream>>>(x, xb, nx);
    cvt4_kernel<<<dim3(nw / 4 / 256, 4), 256, 0, stream>>>(
        Wq, Wk, Wv, Wo, wqkv, wqkv + nw, wqkv + 2 * nw, wob, nw);

    gemm_qkv<<<dim3(24, M_TOT / 128), 256, 0, stream>>>(xb, wqkv, Qb, Kb, VTb);
    rope_kernel<<<SEQ, 256, 0, stream>>>(Qb, Kb, pos);
    attn_kernel<<<256, 256, 0, stream>>>(Qb, Kb, VTb, AOb);
    gemm_out<<<dim3(8, M_TOT / 128), 256, 0, stream>>>(AOb, wob, out);
}

// Round 8
// 220.301 us; speedup vs baseline: 1.2224x; 1.1940x over previous
//
#include <hip/hip_runtime.h>
#include <hip/hip_bf16.h>

// MHA forward: B=2, H=16, S=2048, D=1024, d_k=64, causal, RoPE(theta=1e4)
// R7 -> R8:
//  - attn: 512 blocks x 4 waves (8 waves/CU, was 4), 64-row q-tiles paired {j,31-j}
//          (33 iters/block), 1 sub/wave; softmax VALU diet: Q pre-scaled by 1/8 in
//          RoPE, diagonal-tile-only mask, per-lane l accumulation (epilogue reduce),
//          defer-max THR=8; DMA dbuf staging + XOR swizzle kept.
//  - gemm: revert to BK=32 m97-style core (R7's BK=64+swizzle measured slower);
//          merged QKV single dispatch kept.

typedef __bf16 bf16x8 __attribute__((ext_vector_type(8)));
typedef __bf16 bf16x4 __attribute__((ext_vector_type(4)));
typedef float f32x4 __attribute__((ext_vector_type(4)));
typedef unsigned short ushort8 __attribute__((ext_vector_type(8)));

#define BATCH 2
#define SEQ 2048
#define NH 16
#define DK 64
#define DM 1024
#define BH (BATCH*NH)
#define M_TOT (BATCH*SEQ)   // 4096

__device__ __forceinline__ void gload16(const void* g, void* l) {
    // async global->LDS, 16B/lane; LDS dest = wave-uniform base + lane*16
    __builtin_amdgcn_global_load_lds((const __attribute__((address_space(1))) void*)g,
                                     (__attribute__((address_space(3))) void*)l, 16, 0, 0);
}

// ---------------- fp32 -> bf16 converts ----------------
__global__ void cvt_kernel(const float* __restrict__ s, __bf16* __restrict__ d, int n) {
    int i = (blockIdx.x * blockDim.x + threadIdx.x) * 4;
    if (i >= n) return;
    float4 v = *(const float4*)(s + i);
    bf16x4 o;
    o[0] = (__bf16)v.x; o[1] = (__bf16)v.y; o[2] = (__bf16)v.z; o[3] = (__bf16)v.w;
    *(bf16x4*)(d + i) = o;
}

__global__ void cvt4_kernel(const float* __restrict__ s0, const float* __restrict__ s1,
                            const float* __restrict__ s2, const float* __restrict__ s3,
                            __bf16* __restrict__ d0, __bf16* __restrict__ d1,
                            __bf16* __restrict__ d2, __bf16* __restrict__ d3, int n) {
    const int z = blockIdx.y;
    const float* s = (z == 0) ? s0 : (z == 1) ? s1 : (z == 2) ? s2 : s3;
    __bf16* d = (z == 0) ? d0 : (z == 1) ? d1 : (z == 2) ? d2 : d3;
    int i = (blockIdx.x * blockDim.x + threadIdx.x) * 4;
    if (i >= n) return;
    float4 v = *(const float4*)(s + i);
    bf16x4 o;
    o[0] = (__bf16)v.x; o[1] = (__bf16)v.y; o[2] = (__bf16)v.z; o[3] = (__bf16)v.w;
    *(bf16x4*)(d + i) = o;
}

// ---------------- GEMM core (R5/R6 proven): BK=32, linear [128][32] LDS ----------------
__device__ __forceinline__ void gemm_tile_compute(
    const __bf16* __restrict__ A, const __bf16* __restrict__ W,
    int m0, int n0, int K, __bf16* sA, __bf16* sB, f32x4 (&acc)[4][4])
{
    const int t = threadIdx.x;
    const int lane = t & 63, wid = t >> 6;
    const int wr = wid >> 1, wc = wid & 1;
    const int g = lane >> 4, l15 = lane & 15;

    f32x4 zero = {0.f, 0.f, 0.f, 0.f};
#pragma unroll
    for (int mt = 0; mt < 4; ++mt)
#pragma unroll
        for (int nt = 0; nt < 4; ++nt) acc[mt][nt] = zero;

    for (int k0 = 0; k0 < K; k0 += 32) {
        __syncthreads();
#pragma unroll
        for (int rnd = 0; rnd < 2; ++rnd) {
            int s = rnd * 256 + t;
            int row = s >> 2, ch = s & 3;
            __bf16* dstA = sA + (rnd * 256 + wid * 64) * 8;
            __bf16* dstB = sB + (rnd * 256 + wid * 64) * 8;
            gload16(A + (size_t)(m0 + row) * K + k0 + ch * 8, dstA);
            gload16(W + (size_t)(n0 + row) * K + k0 + ch * 8, dstB);
        }
        __syncthreads();
        bf16x8 af[4], bfr[4];
#pragma unroll
        for (int mt = 0; mt < 4; ++mt)
            af[mt] = *(const bf16x8*)&sA[(wr * 64 + mt * 16 + l15) * 32 + g * 8];
#pragma unroll
        for (int nt = 0; nt < 4; ++nt)
            bfr[nt] = *(const bf16x8*)&sB[(wc * 64 + nt * 16 + l15) * 32 + g * 8];
#pragma unroll
        for (int mt = 0; mt < 4; ++mt)
#pragma unroll
            for (int nt = 0; nt < 4; ++nt)
                acc[mt][nt] = __builtin_amdgcn_mfma_f32_16x16x32_bf16(af[mt], bfr[nt], acc[mt][nt], 0, 0, 0);
    }
}

// Merged QKV GEMM: W = [Wq;Wk;Wv] rows 0..3071. Q/K [B,H,S,dk], V^T [B,H,dk,S].
__global__ __launch_bounds__(256) void gemm_qkv(
    const __bf16* __restrict__ xb, const __bf16* __restrict__ wqkv,
    __bf16* __restrict__ Qb, __bf16* __restrict__ Kb, __bf16* __restrict__ VTb)
{
    __shared__ __align__(16) __bf16 sA[128 * 32], sB[128 * 32];
    int id = blockIdx.x + 24 * blockIdx.y;       // 0..767
    id = (id & 7) * 96 + (id >> 3);              // XCD-contiguous (768%8==0)
    const int m0 = (id / 24) * 128, n0 = (id % 24) * 128;

    f32x4 acc[4][4];
    gemm_tile_compute(xb, wqkv, m0, n0, DM, sA, sB, acc);

    const int t = threadIdx.x, lane = t & 63, wid = t >> 6;
    const int wr = wid >> 1, wc = wid & 1, g = lane >> 4, l15 = lane & 15;
#pragma unroll
    for (int mt = 0; mt < 4; ++mt)
#pragma unroll
        for (int nt = 0; nt < 4; ++nt)
#pragma unroll
            for (int r = 0; r < 4; ++r) {
                int m = m0 + wr * 64 + mt * 16 + g * 4 + r;   // (b, s)
                int n = n0 + wc * 64 + nt * 16 + l15;         // 0..3071
                int z = n >> 10, hd = n & 1023, h = hd >> 6, d = hd & 63;
                int b = m >> 11, s = m & 2047;
                __bf16 v = (__bf16)acc[mt][nt][r];
                if (z == 0)
                    Qb[(((size_t)(b * NH + h)) * SEQ + s) * DK + d] = v;
                else if (z == 1)
                    Kb[(((size_t)(b * NH + h)) * SEQ + s) * DK + d] = v;
                else
                    VTb[(((size_t)(b * NH + h)) * DK + d) * SEQ + s] = v;
            }
}

// Output GEMM: out[M,1024] fp32 = AO[M,1024]bf16 @ Wo^T
__global__ __launch_bounds__(256) void gemm_out(
    const __bf16* __restrict__ AO, const __bf16* __restrict__ wo, float* __restrict__ out)
{
    __shared__ __align__(16) __bf16 sA[128 * 32], sB[128 * 32];
    int id = blockIdx.x + 8 * blockIdx.y;        // 0..255
    id = (id & 7) * 32 + (id >> 3);              // XCD-contiguous
    const int m0 = (id / 8) * 128, n0 = (id % 8) * 128;

    f32x4 acc[4][4];
    gemm_tile_compute(AO, wo, m0, n0, DM, sA, sB, acc);

    const int t = threadIdx.x, lane = t & 63, wid = t >> 6;
    const int wr = wid >> 1, wc = wid & 1, g = lane >> 4, l15 = lane & 15;
#pragma unroll
    for (int mt = 0; mt < 4; ++mt)
#pragma unroll
        for (int nt = 0; nt < 4; ++nt)
#pragma unroll
            for (int r = 0; r < 4; ++r) {
                int m = m0 + wr * 64 + mt * 16 + g * 4 + r;
                int n = n0 + wc * 64 + nt * 16 + l15;
                out[(size_t)m * DM + n] = acc[mt][nt][r];
            }
}

// ---------------- RoPE (in-place; Q additionally scaled by 1/8 = 1/sqrt(dk)) ----------------
__global__ __launch_bounds__(256) void rope_kernel(
    __bf16* __restrict__ Qb, __bf16* __restrict__ Kb, const int* __restrict__ pos)
{
    __shared__ float ctab[32], stab[32];
    const int s = blockIdx.x;
    const int t = threadIdx.x;
    if (t < 32) {
        float invf = exp2f(-13.287712379549449f * (float)t * (1.0f / 32.0f));
        float ang = (float)pos[s] * invf;
        float sn, cs;
        sincosf(ang, &sn, &cs);
        ctab[t] = cs; stab[t] = sn;
    }
    __syncthreads();
#pragma unroll
    for (int u = 0; u < 8; ++u) {
        int id = u * 256 + t;
        int i = id & 31;
        int bh = (id >> 5) & 31;
        int isK = id >> 10;
        __bf16* P = isK ? Kb : Qb;
        float qs = isK ? 1.0f : 0.125f;    // fold 1/sqrt(dk) into Q (exact in bf16)
        __bf16* p = P + ((size_t)bh * SEQ + s) * DK + i * 2;
        float x1 = (float)p[0], x2 = (float)p[1];
        float c = ctab[i], sn = stab[i];
        p[0] = (__bf16)(qs * (x1 * c - x2 * sn));
        p[1] = (__bf16)(qs * (x1 * sn + x2 * c));
    }
}

// ---------------- Flash attention ----------------
// grid 512: xcd = n&7 (4 bh per XCD), slot = n>>3: bh = xcd*4 + slot>>4, x = slot&15.
// Phases j = x, 31-x over 64-row q-tiles -> 33 iters per block (balanced).
// Block: 4 waves x 16 q-rows. K/V dbuf DMA-staged (linear dest, inv-swizzled src).
// Defer-max THR=8; per-lane l accumulation, reduced once in epilogue.
__global__ __launch_bounds__(256, 2) void attn_kernel(
    const __bf16* __restrict__ Qb, const __bf16* __restrict__ Kb,
    const __bf16* __restrict__ VTb, __bf16* __restrict__ AO)
{
    __shared__ __align__(16) __bf16 sK[2][64 * 64];       // [buf][kv][d] swizzled
    __shared__ __align__(16) __bf16 sV[2][64 * 64];       // [buf][d][kv] swizzled
    __shared__ __align__(16) __bf16 sP[4 * 16 * 64];      // [wave][16 q][64 kv] swizzled

    const int n = blockIdx.x;                  // 0..511
    const int xcd = n & 7, slot = n >> 3;      // 64 slots per XCD
    const int bh = xcd * 4 + (slot >> 4);
    const int x = slot & 15;                   // pair index 0..15
    const int t = threadIdx.x, lane = t & 63, wid = t >> 6;
    const int g = lane >> 4, l15 = lane & 15;

    const size_t baseQK = (size_t)bh * SEQ * DK;
    const size_t baseVT = (size_t)bh * DK * SEQ;
    const int b = bh >> 4, h = bh & 15;

    const char* Kt0 = (const char*)(Kb + baseQK);
    const char* Vt0 = (const char*)(VTb + baseVT);
    char* myP = (char*)sP + wid * 2048;
    f32x4 zero = {0.f, 0.f, 0.f, 0.f};

    auto stage_tile = [&](int kt, int bq) {
        const char* Kt = Kt0 + (size_t)kt * 64 * 128;
        const char* Vt = Vt0 + (size_t)kt * 128;
#pragma unroll
        for (int cc = 0; cc < 2; ++cc) {
            int c = t + cc * 256;
            int r = c >> 3, pp = c & 7;
            int p = pp ^ (r & 7);              // involution: source chunk
            char* bK = (char*)sK[bq] + (cc * 256 + wid * 64) * 16;
            char* bV = (char*)sV[bq] + (cc * 256 + wid * 64) * 16;
            gload16(Kt + (size_t)r * 128 + p * 16, bK);
            gload16(Vt + (size_t)r * (SEQ * 2) + p * 16, bV);
        }
    };

    for (int ph = 0; ph < 2; ++ph) {
        const int j = ph ? (31 - x) : x;       // 64-row q-tile index 0..31
        const int qrow_w = j * 64 + wid * 16;  // wave's q rows [qrow_w, qrow_w+16)
        const int ktmax = j;

        // Q fragments (pre-scaled by 1/8 in RoPE)
        bf16x8 qf[2];
        {
            const __bf16* qp = Qb + baseQK + (size_t)(qrow_w + l15) * DK;
            qf[0] = *(const bf16x8*)(qp + g * 8);
            qf[1] = *(const bf16x8*)(qp + 32 + g * 8);
        }

        f32x4 oacc[4];
        float mrow[4], lacc[4];
#pragma unroll
        for (int dt = 0; dt < 4; ++dt) oacc[dt] = zero;
#pragma unroll
        for (int r = 0; r < 4; ++r) { mrow[r] = -3e38f; lacc[r] = 0.f; }

        stage_tile(0, 0);
        __syncthreads();
        int cur = 0;

        for (int kt = 0; kt <= ktmax; ++kt) {
            if (kt < ktmax) stage_tile(kt + 1, cur ^ 1);   // DMA overlaps compute

            // ---- S = Q K^T (pre-scaled) ----
            f32x4 sacc[4];
#pragma unroll
            for (int nt = 0; nt < 4; ++nt) {
                sacc[nt] = zero;
                int row = nt * 16 + l15;
#pragma unroll
                for (int ks = 0; ks < 2; ++ks) {
                    bf16x8 kf = *(const bf16x8*)((const char*)sK[cur] + row * 128 +
                                                 ((ks * 64 + g * 16) ^ ((row & 7) << 4)));
                    sacc[nt] = __builtin_amdgcn_mfma_f32_16x16x32_bf16(qf[ks], kf, sacc[nt], 0, 0, 0);
                }
            }

            // ---- causal mask: only the diagonal tile ----
            if (kt == ktmax) {
#pragma unroll
                for (int nt = 0; nt < 4; ++nt)
#pragma unroll
                    for (int r = 0; r < 4; ++r) {
                        int kv = kt * 64 + nt * 16 + l15;
                        int q = qrow_w + g * 4 + r;
                        if (kv > q) sacc[nt][r] = -3e38f;
                    }
            }

            // ---- online softmax, defer-max (THR=8), per-lane l accumulation ----
#pragma unroll
            for (int r = 0; r < 4; ++r) {
                float tm = fmaxf(fmaxf(sacc[0][r], sacc[1][r]), fmaxf(sacc[2][r], sacc[3][r]));
#pragma unroll
                for (int msk = 1; msk < 16; msk <<= 1) tm = fmaxf(tm, __shfl_xor(tm, msk));
                if (tm > mrow[r] + 8.0f) {     // rare rescale (uniform per 16-lane group)
                    float sc = __expf(mrow[r] - tm);
                    mrow[r] = tm;
                    lacc[r] *= sc;
#pragma unroll
                    for (int dt = 0; dt < 4; ++dt) oacc[dt][r] *= sc;
                }
#pragma unroll
                for (int nt = 0; nt < 4; ++nt) {
                    float p = __expf(sacc[nt][r] - mrow[r]);
                    sacc[nt][r] = p;
                    lacc[r] += p;
                }
            }

            // ---- P -> per-wave LDS (swizzled); same-wave DS in-order ----
#pragma unroll
            for (int nt = 0; nt < 4; ++nt)
#pragma unroll
                for (int r = 0; r < 4; ++r) {
                    int row = g * 4 + r;
                    *(__bf16*)(myP + row * 128 +
                               ((nt * 32 + l15 * 2) ^ ((row & 7) << 4))) = (__bf16)sacc[nt][r];
                }

            // ---- O += P V ----
#pragma unroll
            for (int ks = 0; ks < 2; ++ks) {
                bf16x8 pf = *(const bf16x8*)(myP + l15 * 128 +
                                             ((ks * 64 + g * 16) ^ ((l15 & 7) << 4)));
#pragma unroll
                for (int dt = 0; dt < 4; ++dt) {
                    int row = dt * 16 + l15;
                    bf16x8 vf = *(const bf16x8*)((const char*)sV[cur] + row * 128 +
                                                 ((ks * 64 + g * 16) ^ ((row & 7) << 4)));
                    oacc[dt] = __builtin_amdgcn_mfma_f32_16x16x32_bf16(pf, vf, oacc[dt], 0, 0, 0);
                }
            }

            __syncthreads();   // DMA drained (next buf ready) + all waves done with cur
            cur ^= 1;
        }

        // ---- epilogue: reduce l across 16 lanes, O /= l, write AO ----
#pragma unroll
        for (int r = 0; r < 4; ++r) {
            float rs = lacc[r];
#pragma unroll
            for (int msk = 1; msk < 16; msk <<= 1) rs += __shfl_xor(rs, msk);
            float inv = 1.0f / rs;
            int srow = qrow_w + g * 4 + r;
            size_t obase = ((size_t)b * SEQ + srow) * DM + h * DK;
#pragma unroll
            for (int dt = 0; dt < 4; ++dt)
                AO[obase + dt * 16 + l15] = (__bf16)(oacc[dt][r] * inv);
        }
    }
}

// ---------------- launch ----------------
extern "C" void kernel_launch(void* const* d_in, const int* in_sizes, int n_in,
                              void* d_out, int out_size, void* d_ws, size_t ws_size,
                              hipStream_t stream) {
    (void)in_sizes; (void)n_in; (void)out_size; (void)ws_size;
    const float* x  = (const float*)d_in[0];
    const int*  pos = (const int*)d_in[1];
    const float* Wq = (const float*)d_in[2];
    const float* Wk = (const float*)d_in[3];
    const float* Wv = (const float*)d_in[4];
    const float* Wo = (const float*)d_in[5];
    float* out = (float*)d_out;

    char* ws = (char*)d_ws;
    __bf16* xb   = (__bf16*)ws; ws += (size_t)M_TOT * DM * 2;
    __bf16* wqkv = (__bf16*)ws; ws += (size_t)3 * DM * DM * 2;
    __bf16* wob  = (__bf16*)ws; ws += (size_t)DM * DM * 2;
    __bf16* Qb   = (__bf16*)ws; ws += (size_t)BH * SEQ * DK * 2;
    __bf16* Kb   = (__bf16*)ws; ws += (size_t)BH * SEQ * DK * 2;
    __bf16* VTb  = (__bf16*)ws; ws += (size_t)BH * SEQ * DK * 2;
    __bf16* AOb  = (__bf16*)ws; ws += (size_t)M_TOT * DM * 2;

    const int nx = M_TOT * DM, nw = DM * DM;
    cvt_kernel<<<nx / 4 / 256, 256, 0, stream>>>(x, xb, nx);
    cvt4_kernel<<<dim3(nw / 4 / 256, 4), 256, 0, stream>>>(
        Wq, Wk, Wv, Wo, wqkv, wqkv + nw, wqkv + 2 * nw, wob, nw);

    gemm_qkv<<<dim3(24, M_TOT / 128), 256, 0, stream>>>(xb, wqkv, Qb, Kb, VTb);
    rope_kernel<<<SEQ, 256, 0, stream>>>(Qb, Kb, pos);
    attn_kernel<<<512, 256, 0, stream>>>(Qb, Kb, VTb, AOb);
    gemm_out<<<dim3(8, M_TOT / 128), 256, 0, stream>>>(AOb, wob, out);
}